// Round 11
// baseline (231.838 us; speedup 1.0000x reference)
//
#include <hip/hip_runtime.h>
#include <stdint.h>
#include <stddef.h>

using f16 = _Float16;
typedef __attribute__((ext_vector_type(8))) _Float16 f16x8;
typedef __attribute__((ext_vector_type(4))) float f32x4;

// ---------------------------------------------------------------------------
__device__ __forceinline__ void async_copy16(const f16* g, f16* l) {
    __builtin_amdgcn_global_load_lds(
        (const __attribute__((address_space(1))) void*)g,
        (__attribute__((address_space(3))) void*)l, 16, 0, 0);
}

template <int N>
__device__ __forceinline__ void wait_vmcnt() {
    if constexpr (N == 0)       asm volatile("s_waitcnt vmcnt(0)" ::: "memory");
    else if constexpr (N == 6)  asm volatile("s_waitcnt vmcnt(6)" ::: "memory");
    else if constexpr (N == 8)  asm volatile("s_waitcnt vmcnt(8)" ::: "memory");
}

__device__ __forceinline__ void hard_barrier() {
    __builtin_amdgcn_sched_barrier(0);
    __builtin_amdgcn_s_barrier();
    __builtin_amdgcn_sched_barrier(0);
}

// ---------------------------------------------------------------------------
// Weight prep, 6144 blocks: z<3 f16 convert (Wq,Wk,Wv), z>=3 f16 transpose
// (Wo, mlp_in, mlp_out). (R8-proven packing.)
__global__ __launch_bounds__(256)
void prep_w(const float* __restrict__ w0, const float* __restrict__ w1,
            const float* __restrict__ w2, const float* __restrict__ w3,
            const float* __restrict__ w4, const float* __restrict__ w5,
            f16* o0, f16* o1, f16* o2, f16* o3, f16* o4, f16* o5, int D) {
    __shared__ float tile[32][33];
    const int tx = threadIdx.x & 31, ty = threadIdx.x >> 5;
    const int b = blockIdx.x;
    const int z = b >> 10, r = b & 1023;
    const float* in = z == 0 ? w0 : z == 1 ? w1 : z == 2 ? w2 : z == 3 ? w3 : z == 4 ? w4 : w5;
    f16* out = z == 0 ? o0 : z == 1 ? o1 : z == 2 ? o2 : z == 3 ? o3 : z == 4 ? o4 : o5;
    const int c0 = (r & 31) * 32, r0 = (r >> 5) * 32;
    if (z < 3) {
#pragma unroll
        for (int j = 0; j < 4; j++) {
            size_t idx = (size_t)(r0 + ty + j * 8) * D + c0 + tx;
            out[idx] = (f16)in[idx];
        }
    } else {
#pragma unroll
        for (int j = 0; j < 4; j++)
            tile[ty + j * 8][tx] = in[(size_t)(r0 + ty + j * 8) * D + c0 + tx];
        __syncthreads();
#pragma unroll
        for (int j = 0; j < 4; j++)
            out[(size_t)(c0 + ty + j * 8) * D + r0 + tx] = (f16)tile[tx][ty + j * 8];
    }
}

// ---------------------------------------------------------------------------
// 64x64x128-step fp16 GEMM body, double-buffered+swizzled (tiny stage only).
__device__ __forceinline__ void body64db(
    f16* lds, const f16* __restrict__ A, const f16* __restrict__ B,
    f16* __restrict__ Ch, int m0, int n0, int N, int K, int lda) {
    const int t = threadIdx.x;
    const int lane = t & 63, wave = t >> 6;
    const int wm = (wave >> 1) * 32, wn = (wave & 1) * 32;
    const int lm = lane & 15, lq = lane >> 4;
    const int srow = t >> 2;
    const int gs = ((t & 3) ^ ((srow >> 1) & 3)) * 8;
    const int rs = (lq ^ ((lm >> 1) & 3)) * 8;

    auto stage = [&](f16* buf, int k0) {
#pragma unroll
        for (int r = 0; r < 4; r++)
            async_copy16(A + (size_t)(m0 + srow) * lda + k0 + r * 32 + gs,
                         buf + r * 2048 + t * 8);
#pragma unroll
        for (int r = 0; r < 4; r++)
            async_copy16(B + (size_t)(n0 + srow) * K + k0 + r * 32 + gs,
                         buf + 8192 + r * 2048 + t * 8);
    };

    f32x4 acc[2][2] = {};
    stage(lds, 0);
    __syncthreads();
    int cur = 0;
    for (int k0 = 0; k0 < K; k0 += 128) {
        f16* cb = lds + cur * 16384;
        if (k0 + 128 < K) stage(lds + (cur ^ 1) * 16384, k0 + 128);
#pragma unroll
        for (int kk = 0; kk < 4; kk++) {
            f16x8 af[2], bf[2];
#pragma unroll
            for (int i = 0; i < 2; i++)
                af[i] = *(const f16x8*)&cb[kk * 2048 + (wm + i * 16 + lm) * 32 + rs];
#pragma unroll
            for (int j = 0; j < 2; j++)
                bf[j] = *(const f16x8*)&cb[8192 + kk * 2048 + (wn + j * 16 + lm) * 32 + rs];
#pragma unroll
            for (int i = 0; i < 2; i++)
#pragma unroll
                for (int j = 0; j < 2; j++)
                    acc[i][j] = __builtin_amdgcn_mfma_f32_16x16x32_f16(
                        af[i], bf[j], acc[i][j], 0, 0, 0);
        }
        __syncthreads();
        cur ^= 1;
    }

#pragma unroll
    for (int i = 0; i < 2; i++) {
        const int row = m0 + wm + i * 16 + lq * 4;
#pragma unroll
        for (int j = 0; j < 2; j++) {
            const int col = n0 + wn + j * 16 + lm;
            f32x4 v = acc[i][j];
#pragma unroll
            for (int r = 0; r < 4; r++)
                Ch[(size_t)(row + r) * N + col] = (f16)v[r];
        }
    }
}

// ---------------------------------------------------------------------------
// Fused: X-transpose (blocks 0..4095) ++ tiny GT/HT GEMMs (4096..4607).
__global__ __launch_bounds__(256, 2)
void prepx_tiny(const float* __restrict__ X, f16* __restrict__ Xth,
                const f16* Wkh, const f16* Wqh, f16* GT,
                const f16* Wot, const f16* Wvh, f16* HT, int D, int NT) {
    __shared__ alignas(16) f16 smem[32768];
    int b = blockIdx.x;
    if (b < 4096) {
        float* tile = (float*)smem;  // [32][33]
        const int tx = threadIdx.x & 31, ty = threadIdx.x >> 5;
        const int c0 = (b & 127) * 32, r0 = (b >> 7) * 32;  // c over NT, r over D
#pragma unroll
        for (int j = 0; j < 4; j++)
            tile[(ty + j * 8) * 33 + tx] = X[(size_t)(r0 + ty + j * 8) * NT + c0 + tx];
        __syncthreads();
#pragma unroll
        for (int j = 0; j < 4; j++)
            Xth[(size_t)(c0 + ty + j * 8) * D + r0 + tx] = (f16)tile[tx * 33 + ty + j * 8];
        return;
    }
    b -= 4096;  // 0..511
    if (b < 256)
        body64db(smem, Wkh, Wqh, GT, (b >> 4) * 64, (b & 15) * 64, 1024, 1024, 1024);
    else {
        const int r = b - 256;
        body64db(smem, Wot, Wvh, HT, (r >> 4) * 64, (r & 15) * 64, 1024, 1024, 1024);
    }
}

// ---------------------------------------------------------------------------
// Causal softmax, WAVE-per-row (no block barriers): 1024 blocks x 4 waves.
// Each wave owns row = blockIdx*4 + waveId; reductions via __shfl_xor.
// Zero-fill to lim = ceil128(row+1) — exactly the span A@RH reads.
__global__ __launch_bounds__(256)
void softmax_waves(f16* __restrict__ A, int N) {
    const int wid = threadIdx.x >> 6, lane = threadIdx.x & 63;
    const int row = blockIdx.x * 4 + wid;
    const int len = row + 1;
    const int lim = ((row >> 7) + 1) << 7;
    f16* a = A + (size_t)row * N;

    f16x8 x[8];
#pragma unroll
    for (int c = 0; c < 8; c++)
#pragma unroll
        for (int e = 0; e < 8; e++) x[c][e] = (f16)0;

    float mx = -1e30f;
#pragma unroll
    for (int c = 0; c < 8; c++) {
        const int col = c * 512 + lane * 8;
        if (col < len) {
            x[c] = *(const f16x8*)(a + col);
#pragma unroll
            for (int e = 0; e < 8; e++)
                if (col + e < len) mx = fmaxf(mx, (float)x[c][e]);
        }
    }
#pragma unroll
    for (int o = 32; o > 0; o >>= 1)
        mx = fmaxf(mx, __shfl_xor(mx, o, 64));

    float sum = 0.f;
#pragma unroll
    for (int c = 0; c < 8; c++) {
        const int col = c * 512 + lane * 8;
        if (col < len) {
#pragma unroll
            for (int e = 0; e < 8; e++)
                if (col + e < len) sum += __expf((float)x[c][e] - mx);
        }
    }
#pragma unroll
    for (int o = 32; o > 0; o >>= 1)
        sum += __shfl_xor(sum, o, 64);
    const float inv = 1.0f / sum;

#pragma unroll
    for (int c = 0; c < 8; c++) {
        const int col = c * 512 + lane * 8;
        if (col < lim) {
            f16x8 o8;
#pragma unroll
            for (int e = 0; e < 8; e++) {
                float v = (col + e < len) ? __expf((float)x[c][e] - mx) * inv : 0.0f;
                o8[e] = (f16)v;
            }
            *(f16x8*)(a + col) = o8;
        }
    }
}

// ---------------------------------------------------------------------------
// Swizzle (proven, conflicts 0): LDS [kk][row][32] f16; k-group g of row r
// stored at slot g ^ ((r>>1)&3); applied to global source col (gs) and
// ds_read slot (rs); gload_lds dest stays linear.
// ---------------------------------------------------------------------------

// 128x128 tile, BK=64, 4 waves each 64x64 (acc 4x4). Double-buffered 64 KB,
// counted vmcnt(8) (R5/R8-proven). MODE 0 only.
__device__ __forceinline__ void body128sq(
    f16* lds, const f16* __restrict__ A, const f16* __restrict__ B,
    f16* __restrict__ Ch, int m0, int n0, int N, int K, int lda) {
    constexpr int BUF = 16384;
    const int t = threadIdx.x;
    const int lane = t & 63, wave = t >> 6;
    const int wm = (wave >> 1) * 64, wn = (wave & 1) * 64;
    const int lm = lane & 15, lq = lane >> 4;
    const int srow = t >> 2;
    const int gs = ((t & 3) ^ ((srow >> 1) & 3)) * 8;
    const int rs = (lq ^ ((lm >> 1) & 3)) * 8;

    f32x4 acc[4][4] = {};

    auto stage = [&](f16* buf, int k0) {
#pragma unroll
        for (int r = 0; r < 4; r++)
            async_copy16(A + (size_t)(m0 + (r & 1) * 64 + srow) * lda + k0 + (r >> 1) * 32 + gs,
                         buf + r * 2048 + t * 8);
#pragma unroll
        for (int r = 0; r < 4; r++)
            async_copy16(B + (size_t)(n0 + (r & 1) * 64 + srow) * K + k0 + (r >> 1) * 32 + gs,
                         buf + 8192 + r * 2048 + t * 8);
    };

    auto compute = [&](const f16* cb) {
#pragma unroll
        for (int kk = 0; kk < 2; kk++) {
            f16x8 af[4], bf[4];
#pragma unroll
            for (int i = 0; i < 4; i++)
                af[i] = *(const f16x8*)&cb[kk * 4096 + (wm + i * 16 + lm) * 32 + rs];
#pragma unroll
            for (int j = 0; j < 4; j++)
                bf[j] = *(const f16x8*)&cb[8192 + kk * 4096 + (wn + j * 16 + lm) * 32 + rs];
#pragma unroll
            for (int i = 0; i < 4; i++)
#pragma unroll
                for (int j = 0; j < 4; j++)
                    acc[i][j] = __builtin_amdgcn_mfma_f32_16x16x32_f16(
                        af[i], bf[j], acc[i][j], 0, 0, 0);
        }
    };

    const int NS = K >> 6;
    stage(lds, 0);
    for (int s = 0; s < NS; s++) {
        if (s + 1 < NS) {
            stage(lds + ((s + 1) & 1) * BUF, (s + 1) << 6);
            wait_vmcnt<8>();
        } else {
            wait_vmcnt<0>();
        }
        hard_barrier();
        compute(lds + (s & 1) * BUF);
        if (s + 1 < NS) hard_barrier();
    }

#pragma unroll
    for (int i = 0; i < 4; i++) {
        const int row = m0 + wm + i * 16 + lq * 4;
#pragma unroll
        for (int j = 0; j < 4; j++) {
            const int col = n0 + wn + j * 16 + lm;
            f32x4 v = acc[i][j];
#pragma unroll
            for (int r = 0; r < 4; r++)
                Ch[(size_t)(row + r) * N + col] = (f16)v[r];
        }
    }
}

// ---------------------------------------------------------------------------
// 128x64 tile, BK=64, counted double-buffer 2x24 KB (R8-proven).
// MODE 0: Ch = f16(acc)
// MODE 2: Ch = f16(acc + residH)
// MODE 3: Ch = f16(relu(acc))
// MODE 4: Cf[col*M + row] = acc + residH[row*N + col]  (transposed store)
template <int MODE>
__device__ __forceinline__ void body_nar2(
    f16* lds, const f16* __restrict__ A, const f16* __restrict__ B,
    float* __restrict__ Cf, f16* __restrict__ Ch, const f16* __restrict__ resid,
    int m0, int n0, int M, int N, int K, int lda, int Keff) {
    constexpr int ASZ = 128 * 64;       // 8192 f16
    constexpr int SSZ = ASZ + 64 * 64;  // 12288 f16 = 24 KB per buffer
    const int t = threadIdx.x;
    const int lane = t & 63, wave = t >> 6;
    const int wm = (wave >> 1) * 64, wn = (wave & 1) * 32;
    const int lm = lane & 15, lq = lane >> 4;
    const int srow = t >> 2;
    const int gs = ((t & 3) ^ ((srow >> 1) & 3)) * 8;
    const int rs = (lq ^ ((lm >> 1) & 3)) * 8;

    f32x4 acc[4][2] = {};

    auto stage = [&](f16* buf, int k0) {
#pragma unroll
        for (int r = 0; r < 4; r++)
            async_copy16(A + (size_t)(m0 + (r & 1) * 64 + srow) * lda + k0 + (r >> 1) * 32 + gs,
                         buf + r * 2048 + t * 8);
#pragma unroll
        for (int r = 0; r < 2; r++)
            async_copy16(B + (size_t)(n0 + srow) * K + k0 + r * 32 + gs,
                         buf + ASZ + r * 2048 + t * 8);
    };

    auto compute = [&](const f16* cb) {
#pragma unroll
        for (int kk = 0; kk < 2; kk++) {
            f16x8 af[4], bf[2];
#pragma unroll
            for (int i = 0; i < 4; i++)
                af[i] = *(const f16x8*)&cb[kk * 4096 + (wm + i * 16 + lm) * 32 + rs];
#pragma unroll
            for (int j = 0; j < 2; j++)
                bf[j] = *(const f16x8*)&cb[ASZ + kk * 2048 + (wn + j * 16 + lm) * 32 + rs];
#pragma unroll
            for (int i = 0; i < 4; i++)
#pragma unroll
                for (int j = 0; j < 2; j++)
                    acc[i][j] = __builtin_amdgcn_mfma_f32_16x16x32_f16(
                        af[i], bf[j], acc[i][j], 0, 0, 0);
        }
    };

    stage(lds, 0);
    const int NS = Keff >> 6;
    for (int s = 0; s < NS; s++) {
        if (s + 1 < NS) {
            stage(lds + ((s + 1) & 1) * SSZ, (s + 1) << 6);
            wait_vmcnt<6>();
        } else {
            wait_vmcnt<0>();
        }
        hard_barrier();
        compute(lds + (s & 1) * SSZ);
        hard_barrier();
    }

#pragma unroll
    for (int i = 0; i < 4; i++) {
        const int row = m0 + wm + i * 16 + lq * 4;
#pragma unroll
        for (int j = 0; j < 2; j++) {
            const int col = n0 + wn + j * 16 + lm;
            f32x4 v = acc[i][j];
#pragma unroll
            for (int r = 0; r < 4; r++) {
                if (MODE == 0) {
                    Ch[(size_t)(row + r) * N + col] = (f16)v[r];
                } else if (MODE == 2) {
                    float o = v[r] + (float)resid[(size_t)(row + r) * N + col];
                    Ch[(size_t)(row + r) * N + col] = (f16)o;
                } else if (MODE == 3) {
                    Ch[(size_t)(row + r) * N + col] = (f16)fmaxf(v[r], 0.0f);
                } else {
                    float o = v[r] + (float)resid[(size_t)(row + r) * N + col];
                    Cf[(size_t)col * M + (row + r)] = o;
                }
            }
        }
    }
}

// ---------------------------------------------------------------------------
// Q' = Xt*G^T [4096,1024,1024], 128x64 tiles, 512 blocks.
__global__ __launch_bounds__(256, 2)
void midq(const f16* Xth, const f16* GT, f16* Qp) {
    __shared__ alignas(16) f16 smem[24576];
    const int x = blockIdx.x & 7, s = blockIdx.x >> 3;  // 0..63
    const int m = x + 8 * (s >> 4), n = s & 15;
    body_nar2<0>(smem, Xth, GT, nullptr, Qp, nullptr,
                 m * 128, n * 64, 4096, 1024, 1024, 1024, 1024);
}

// ---------------------------------------------------------------------------
// Fused: scores (lower triangle, blocks 0..527) ++ RHt = HT*Xt^T (528..783).
// midrh blocks backfill into the long scores launch (R5/R8-proven).
__global__ __launch_bounds__(256, 2)
void scores_midrh(const f16* Qp, const f16* Xth, f16* Af,
                  const f16* HT, f16* RHt) {
    __shared__ alignas(16) f16 smem[32768];
    int b = blockIdx.x;
    if (b < 528) {
        const int x = b & 7;
        int s = b >> 3;  // 0..65
        int m = 0, n = 0;
#pragma unroll
        for (int q = 3; q >= 0; q--) {
            const int mm = 8 * q + ((q & 1) ? 7 - x : x);
            if (s < mm + 1) { m = mm; n = s; break; }
            s -= mm + 1;
        }
        body128sq(smem, Qp, Xth, Af, m * 128, n * 128, 4096, 1024, 1024);
    } else {
        const int r = b - 528;  // 0..255
        const int x = r & 7;
        const int s = r >> 3;   // 0..31
        const int n = x + 8 * (s >> 3), m = s & 7;
        body128sq(smem, HT, Xth, RHt, m * 128, n * 128, 4096, 1024, 1024);
    }
}

// Narrow GEMMs [M=4096, N=1024], 128x64 tiles, 512 blocks.
// CAUSAL: q-permutation {3,2,0,1} + zigzag balances K-work across CUs.
template <int MODE, bool CAUSAL_K>
__global__ __launch_bounds__(256, 2)
void gemm_nar(const f16* __restrict__ A, const f16* __restrict__ B,
              float* __restrict__ Cf, f16* __restrict__ Ch,
              const f16* __restrict__ resid, int M, int N, int K, int lda) {
    __shared__ alignas(16) f16 smem[24576];
    const int x = blockIdx.x & 7, s = blockIdx.x >> 3;  // s in 0..63
    const int qs = s >> 4, n = s & 15;
    int m;
    if (CAUSAL_K) {
        const int q = (qs == 0) ? 3 : (qs == 1) ? 2 : (qs == 2) ? 0 : 1;
        m = 8 * q + ((q & 1) ? 7 - x : x);
    } else {
        m = x + 8 * qs;
    }
    const int m0 = m * 128, n0 = n * 64;
    int Keff = K;
    if (CAUSAL_K) {
        Keff = m0 + 128;
        if (Keff > K) Keff = K;
    }
    body_nar2<MODE>(smem, A, B, Cf, Ch, resid,
                    m0, n0, M, N, K, lda, Keff);
}

// ---------------------------------------------------------------------------
extern "C" void kernel_launch(void* const* d_in, const int* in_sizes, int n_in,
                              void* d_out, int out_size, void* d_ws, size_t ws_size,
                              hipStream_t stream) {
    const int D = 1024, NT = 4096;
    const float* X = (const float*)d_in[0];
    const float* W[6] = {(const float*)d_in[1], (const float*)d_in[2],
                         (const float*)d_in[3], (const float*)d_in[4],
                         (const float*)d_in[5], (const float*)d_in[6]};
    char* ws = (char*)d_ws;
    auto MB = [](size_t x) { return x << 20; };

    // Workspace (80 MB peak):
    f16*   Xth  = (f16*)(ws + MB(0));      // [NT][D] (also f16 residual)
    f16*   Wqh  = (f16*)(ws + MB(8));
    f16*   Wkh  = (f16*)(ws + MB(10));
    f16*   Wvh  = (f16*)(ws + MB(12));
    f16*   Wot  = (f16*)(ws + MB(14));
    f16*   W4t  = (f16*)(ws + MB(16));
    f16*   W5t  = (f16*)(ws + MB(18));
    f16*   GT   = (f16*)(ws + MB(20));     // [D][D]
    f16*   HT   = (f16*)(ws + MB(22));     // [D][D]
    f16*   Qp   = (f16*)(ws + MB(24));     // [NT][D] (dead after scores)
    f16*   Af   = (f16*)(ws + MB(32));     // [NT][NT] f16 scores -> softmax A
    f16*   RHt  = (f16*)(ws + MB(64));     // [D][NT]
    f16*   Y1h  = (f16*)(ws + MB(72));     // [NT][D]
    f16*   hb   = (f16*)(ws + MB(24));     // over Qp (dead)
    float* outF = (float*)d_out;           // [D][NT]

    // 1. Weight prep (convert + transpose, R8 packing).
    prep_w<<<6144, 256, 0, stream>>>(W[0], W[1], W[2], W[3], W[4], W[5],
                                     Wqh, Wkh, Wvh, Wot, W4t, W5t, D);

    // 2. X-transpose ++ GT = Wk*Wq^T ++ HT = Wo^T*Wv^T (fused, independent).
    prepx_tiny<<<4608, 256, 0, stream>>>(X, Xth, Wkh, Wqh, GT, Wot, Wvh, HT,
                                         D, NT);

    // 3. Q' = Xt*G^T (counted dbuf).
    midq<<<512, 256, 0, stream>>>(Xth, GT, Qp);

    // 4. Scores ++ RHt = HT*Xt^T (fused, R8-proven).
    scores_midrh<<<784, 256, 0, stream>>>(Qp, Xth, Af, HT, RHt);

    // 5. Softmax, wave-per-row (no block barriers).
    softmax_waves<<<1024, 256, 0, stream>>>(Af, NT);

    // 6. Y1 = Xt + A@RH (causal-K truncation, CU-pair-balanced).
    gemm_nar<2, true><<<512, 256, 0, stream>>>(
        Af, RHt, nullptr, Y1h, Xth, NT, D, NT, NT);

    // 7. h = relu(Y1 @ mlp_in).
    gemm_nar<3, false><<<512, 256, 0, stream>>>(
        Y1h, W4t, nullptr, hb, nullptr, NT, D, D, D);

    // 8. out = (Y1 + h @ mlp_out)^T.
    gemm_nar<4, false><<<512, 256, 0, stream>>>(
        hb, W5t, outF, nullptr, Y1h, NT, D, D, D);
}

// Round 12
// 229.407 us; speedup vs baseline: 1.0106x; 1.0106x over previous
//
#include <hip/hip_runtime.h>
#include <stdint.h>
#include <stddef.h>

using f16 = _Float16;
typedef __attribute__((ext_vector_type(8))) _Float16 f16x8;
typedef __attribute__((ext_vector_type(4))) float f32x4;

// ---------------------------------------------------------------------------
__device__ __forceinline__ void async_copy16(const f16* g, f16* l) {
    __builtin_amdgcn_global_load_lds(
        (const __attribute__((address_space(1))) void*)g,
        (__attribute__((address_space(3))) void*)l, 16, 0, 0);
}

template <int N>
__device__ __forceinline__ void wait_vmcnt() {
    if constexpr (N == 0)       asm volatile("s_waitcnt vmcnt(0)" ::: "memory");
    else if constexpr (N == 6)  asm volatile("s_waitcnt vmcnt(6)" ::: "memory");
    else if constexpr (N == 8)  asm volatile("s_waitcnt vmcnt(8)" ::: "memory");
}

__device__ __forceinline__ void hard_barrier() {
    __builtin_amdgcn_sched_barrier(0);
    __builtin_amdgcn_s_barrier();
    __builtin_amdgcn_sched_barrier(0);
}

// ---------------------------------------------------------------------------
// Weight prep, 6144 blocks: z<3 f16 convert (Wq,Wk,Wv), z>=3 f16 transpose
// (Wo, mlp_in, mlp_out). (R8-proven packing.)
__global__ __launch_bounds__(256)
void prep_w(const float* __restrict__ w0, const float* __restrict__ w1,
            const float* __restrict__ w2, const float* __restrict__ w3,
            const float* __restrict__ w4, const float* __restrict__ w5,
            f16* o0, f16* o1, f16* o2, f16* o3, f16* o4, f16* o5, int D) {
    __shared__ float tile[32][33];
    const int tx = threadIdx.x & 31, ty = threadIdx.x >> 5;
    const int b = blockIdx.x;
    const int z = b >> 10, r = b & 1023;
    const float* in = z == 0 ? w0 : z == 1 ? w1 : z == 2 ? w2 : z == 3 ? w3 : z == 4 ? w4 : w5;
    f16* out = z == 0 ? o0 : z == 1 ? o1 : z == 2 ? o2 : z == 3 ? o3 : z == 4 ? o4 : o5;
    const int c0 = (r & 31) * 32, r0 = (r >> 5) * 32;
    if (z < 3) {
#pragma unroll
        for (int j = 0; j < 4; j++) {
            size_t idx = (size_t)(r0 + ty + j * 8) * D + c0 + tx;
            out[idx] = (f16)in[idx];
        }
    } else {
#pragma unroll
        for (int j = 0; j < 4; j++)
            tile[ty + j * 8][tx] = in[(size_t)(r0 + ty + j * 8) * D + c0 + tx];
        __syncthreads();
#pragma unroll
        for (int j = 0; j < 4; j++)
            out[(size_t)(c0 + ty + j * 8) * D + r0 + tx] = (f16)tile[tx][ty + j * 8];
    }
}

// ---------------------------------------------------------------------------
// 64x64x128-step fp16 GEMM body, double-buffered+swizzled (tiny stage only).
__device__ __forceinline__ void body64db(
    f16* lds, const f16* __restrict__ A, const f16* __restrict__ B,
    f16* __restrict__ Ch, int m0, int n0, int N, int K, int lda) {
    const int t = threadIdx.x;
    const int lane = t & 63, wave = t >> 6;
    const int wm = (wave >> 1) * 32, wn = (wave & 1) * 32;
    const int lm = lane & 15, lq = lane >> 4;
    const int srow = t >> 2;
    const int gs = ((t & 3) ^ ((srow >> 1) & 3)) * 8;
    const int rs = (lq ^ ((lm >> 1) & 3)) * 8;

    auto stage = [&](f16* buf, int k0) {
#pragma unroll
        for (int r = 0; r < 4; r++)
            async_copy16(A + (size_t)(m0 + srow) * lda + k0 + r * 32 + gs,
                         buf + r * 2048 + t * 8);
#pragma unroll
        for (int r = 0; r < 4; r++)
            async_copy16(B + (size_t)(n0 + srow) * K + k0 + r * 32 + gs,
                         buf + 8192 + r * 2048 + t * 8);
    };

    f32x4 acc[2][2] = {};
    stage(lds, 0);
    __syncthreads();
    int cur = 0;
    for (int k0 = 0; k0 < K; k0 += 128) {
        f16* cb = lds + cur * 16384;
        if (k0 + 128 < K) stage(lds + (cur ^ 1) * 16384, k0 + 128);
#pragma unroll
        for (int kk = 0; kk < 4; kk++) {
            f16x8 af[2], bf[2];
#pragma unroll
            for (int i = 0; i < 2; i++)
                af[i] = *(const f16x8*)&cb[kk * 2048 + (wm + i * 16 + lm) * 32 + rs];
#pragma unroll
            for (int j = 0; j < 2; j++)
                bf[j] = *(const f16x8*)&cb[8192 + kk * 2048 + (wn + j * 16 + lm) * 32 + rs];
#pragma unroll
            for (int i = 0; i < 2; i++)
#pragma unroll
                for (int j = 0; j < 2; j++)
                    acc[i][j] = __builtin_amdgcn_mfma_f32_16x16x32_f16(
                        af[i], bf[j], acc[i][j], 0, 0, 0);
        }
        __syncthreads();
        cur ^= 1;
    }

#pragma unroll
    for (int i = 0; i < 2; i++) {
        const int row = m0 + wm + i * 16 + lq * 4;
#pragma unroll
        for (int j = 0; j < 2; j++) {
            const int col = n0 + wn + j * 16 + lm;
            f32x4 v = acc[i][j];
#pragma unroll
            for (int r = 0; r < 4; r++)
                Ch[(size_t)(row + r) * N + col] = (f16)v[r];
        }
    }
}

// ---------------------------------------------------------------------------
// Fused: X-transpose (blocks 0..4095) ++ tiny GT/HT GEMMs (4096..4607).
__global__ __launch_bounds__(256, 2)
void prepx_tiny(const float* __restrict__ X, f16* __restrict__ Xth,
                const f16* Wkh, const f16* Wqh, f16* GT,
                const f16* Wot, const f16* Wvh, f16* HT, int D, int NT) {
    __shared__ alignas(16) f16 smem[32768];
    int b = blockIdx.x;
    if (b < 4096) {
        float* tile = (float*)smem;  // [32][33]
        const int tx = threadIdx.x & 31, ty = threadIdx.x >> 5;
        const int c0 = (b & 127) * 32, r0 = (b >> 7) * 32;  // c over NT, r over D
#pragma unroll
        for (int j = 0; j < 4; j++)
            tile[(ty + j * 8) * 33 + tx] = X[(size_t)(r0 + ty + j * 8) * NT + c0 + tx];
        __syncthreads();
#pragma unroll
        for (int j = 0; j < 4; j++)
            Xth[(size_t)(c0 + ty + j * 8) * D + r0 + tx] = (f16)tile[tx * 33 + ty + j * 8];
        return;
    }
    b -= 4096;  // 0..511
    if (b < 256)
        body64db(smem, Wkh, Wqh, GT, (b >> 4) * 64, (b & 15) * 64, 1024, 1024, 1024);
    else {
        const int r = b - 256;
        body64db(smem, Wot, Wvh, HT, (r >> 4) * 64, (r & 15) * 64, 1024, 1024, 1024);
    }
}

// ---------------------------------------------------------------------------
// Causal softmax over f16 A rows IN-PLACE (pitch N). Block-per-row with
// v[16] register cache + single exp (R8-proven layout), but the 16
// block-wide barrier reductions collapse to TWO barriers: wave shfl_xor
// reduce + 4-element LDS exchange (max -> red[0..3], sum -> red[4..7]).
__global__ __launch_bounds__(256)
void softmax_rows(f16* __restrict__ A, int N) {
    const int row = blockIdx.x, len = row + 1;
    const int lim = ((row >> 7) + 1) << 7;
    f16* a = A + (size_t)row * N;
    __shared__ float red[8];
    const int t = threadIdx.x, lane = t & 63, wid = t >> 6;

    float v[16];
    float mx = -1e30f;
#pragma unroll
    for (int j = 0; j < 2; j++) {
        const int c = (t + j * 256) * 8;
        if (c < len) {
            f16x8 x = *(const f16x8*)(a + c);
#pragma unroll
            for (int e = 0; e < 8; e++) {
                float f = (c + e < len) ? (float)x[e] : -1e30f;
                v[j * 8 + e] = f;
                mx = fmaxf(mx, f);
            }
        } else {
#pragma unroll
            for (int e = 0; e < 8; e++) v[j * 8 + e] = -1e30f;
        }
    }
#pragma unroll
    for (int o = 32; o > 0; o >>= 1) mx = fmaxf(mx, __shfl_xor(mx, o, 64));
    if (lane == 0) red[wid] = mx;
    __syncthreads();
    mx = fmaxf(fmaxf(red[0], red[1]), fmaxf(red[2], red[3]));

    float sum = 0.f;
#pragma unroll
    for (int k = 0; k < 16; k++) {
        float e = (v[k] > -1e29f) ? __expf(v[k] - mx) : 0.0f;
        v[k] = e;
        sum += e;
    }
#pragma unroll
    for (int o = 32; o > 0; o >>= 1) sum += __shfl_xor(sum, o, 64);
    if (lane == 0) red[4 + wid] = sum;
    __syncthreads();
    const float inv = 1.0f / (red[4] + red[5] + red[6] + red[7]);

#pragma unroll
    for (int j = 0; j < 2; j++) {
        const int c = (t + j * 256) * 8;
        if (c < lim) {
            f16x8 o8;
#pragma unroll
            for (int e = 0; e < 8; e++) o8[e] = (f16)(v[j * 8 + e] * inv);
            *(f16x8*)(a + c) = o8;
        }
    }
}

// ---------------------------------------------------------------------------
// Swizzle (proven, conflicts 0): LDS [kk][row][32] f16; k-group g of row r
// stored at slot g ^ ((r>>1)&3); applied to global source col (gs) and
// ds_read slot (rs); gload_lds dest stays linear.
// ---------------------------------------------------------------------------

// 128x128 tile, BK=64, 4 waves each 64x64 (acc 4x4). Double-buffered 64 KB,
// counted vmcnt(8) (R5/R8-proven). MODE 0 only.
__device__ __forceinline__ void body128sq(
    f16* lds, const f16* __restrict__ A, const f16* __restrict__ B,
    f16* __restrict__ Ch, int m0, int n0, int N, int K, int lda) {
    constexpr int BUF = 16384;
    const int t = threadIdx.x;
    const int lane = t & 63, wave = t >> 6;
    const int wm = (wave >> 1) * 64, wn = (wave & 1) * 64;
    const int lm = lane & 15, lq = lane >> 4;
    const int srow = t >> 2;
    const int gs = ((t & 3) ^ ((srow >> 1) & 3)) * 8;
    const int rs = (lq ^ ((lm >> 1) & 3)) * 8;

    f32x4 acc[4][4] = {};

    auto stage = [&](f16* buf, int k0) {
#pragma unroll
        for (int r = 0; r < 4; r++)
            async_copy16(A + (size_t)(m0 + (r & 1) * 64 + srow) * lda + k0 + (r >> 1) * 32 + gs,
                         buf + r * 2048 + t * 8);
#pragma unroll
        for (int r = 0; r < 4; r++)
            async_copy16(B + (size_t)(n0 + (r & 1) * 64 + srow) * K + k0 + (r >> 1) * 32 + gs,
                         buf + 8192 + r * 2048 + t * 8);
    };

    auto compute = [&](const f16* cb) {
#pragma unroll
        for (int kk = 0; kk < 2; kk++) {
            f16x8 af[4], bf[4];
#pragma unroll
            for (int i = 0; i < 4; i++)
                af[i] = *(const f16x8*)&cb[kk * 4096 + (wm + i * 16 + lm) * 32 + rs];
#pragma unroll
            for (int j = 0; j < 4; j++)
                bf[j] = *(const f16x8*)&cb[8192 + kk * 4096 + (wn + j * 16 + lm) * 32 + rs];
#pragma unroll
            for (int i = 0; i < 4; i++)
#pragma unroll
                for (int j = 0; j < 4; j++)
                    acc[i][j] = __builtin_amdgcn_mfma_f32_16x16x32_f16(
                        af[i], bf[j], acc[i][j], 0, 0, 0);
        }
    };

    const int NS = K >> 6;
    stage(lds, 0);
    for (int s = 0; s < NS; s++) {
        if (s + 1 < NS) {
            stage(lds + ((s + 1) & 1) * BUF, (s + 1) << 6);
            wait_vmcnt<8>();
        } else {
            wait_vmcnt<0>();
        }
        hard_barrier();
        compute(lds + (s & 1) * BUF);
        if (s + 1 < NS) hard_barrier();
    }

#pragma unroll
    for (int i = 0; i < 4; i++) {
        const int row = m0 + wm + i * 16 + lq * 4;
#pragma unroll
        for (int j = 0; j < 4; j++) {
            const int col = n0 + wn + j * 16 + lm;
            f32x4 v = acc[i][j];
#pragma unroll
            for (int r = 0; r < 4; r++)
                Ch[(size_t)(row + r) * N + col] = (f16)v[r];
        }
    }
}

// ---------------------------------------------------------------------------
// 128x64 tile, BK=64, counted double-buffer 2x24 KB (R8-proven).
// MODE 0: Ch = f16(acc)
// MODE 2: Ch = f16(acc + residH)
// MODE 3: Ch = f16(relu(acc))
// MODE 4: Cf[col*M + row] = acc + residH[row*N + col]  (transposed store)
template <int MODE>
__device__ __forceinline__ void body_nar2(
    f16* lds, const f16* __restrict__ A, const f16* __restrict__ B,
    float* __restrict__ Cf, f16* __restrict__ Ch, const f16* __restrict__ resid,
    int m0, int n0, int M, int N, int K, int lda, int Keff) {
    constexpr int ASZ = 128 * 64;       // 8192 f16
    constexpr int SSZ = ASZ + 64 * 64;  // 12288 f16 = 24 KB per buffer
    const int t = threadIdx.x;
    const int lane = t & 63, wave = t >> 6;
    const int wm = (wave >> 1) * 64, wn = (wave & 1) * 32;
    const int lm = lane & 15, lq = lane >> 4;
    const int srow = t >> 2;
    const int gs = ((t & 3) ^ ((srow >> 1) & 3)) * 8;
    const int rs = (lq ^ ((lm >> 1) & 3)) * 8;

    f32x4 acc[4][2] = {};

    auto stage = [&](f16* buf, int k0) {
#pragma unroll
        for (int r = 0; r < 4; r++)
            async_copy16(A + (size_t)(m0 + (r & 1) * 64 + srow) * lda + k0 + (r >> 1) * 32 + gs,
                         buf + r * 2048 + t * 8);
#pragma unroll
        for (int r = 0; r < 2; r++)
            async_copy16(B + (size_t)(n0 + srow) * K + k0 + r * 32 + gs,
                         buf + ASZ + r * 2048 + t * 8);
    };

    auto compute = [&](const f16* cb) {
#pragma unroll
        for (int kk = 0; kk < 2; kk++) {
            f16x8 af[4], bf[2];
#pragma unroll
            for (int i = 0; i < 4; i++)
                af[i] = *(const f16x8*)&cb[kk * 4096 + (wm + i * 16 + lm) * 32 + rs];
#pragma unroll
            for (int j = 0; j < 2; j++)
                bf[j] = *(const f16x8*)&cb[ASZ + kk * 2048 + (wn + j * 16 + lm) * 32 + rs];
#pragma unroll
            for (int i = 0; i < 4; i++)
#pragma unroll
                for (int j = 0; j < 2; j++)
                    acc[i][j] = __builtin_amdgcn_mfma_f32_16x16x32_f16(
                        af[i], bf[j], acc[i][j], 0, 0, 0);
        }
    };

    stage(lds, 0);
    const int NS = Keff >> 6;
    for (int s = 0; s < NS; s++) {
        if (s + 1 < NS) {
            stage(lds + ((s + 1) & 1) * SSZ, (s + 1) << 6);
            wait_vmcnt<6>();
        } else {
            wait_vmcnt<0>();
        }
        hard_barrier();
        compute(lds + (s & 1) * SSZ);
        hard_barrier();
    }

#pragma unroll
    for (int i = 0; i < 4; i++) {
        const int row = m0 + wm + i * 16 + lq * 4;
#pragma unroll
        for (int j = 0; j < 2; j++) {
            const int col = n0 + wn + j * 16 + lm;
            f32x4 v = acc[i][j];
#pragma unroll
            for (int r = 0; r < 4; r++) {
                if (MODE == 0) {
                    Ch[(size_t)(row + r) * N + col] = (f16)v[r];
                } else if (MODE == 2) {
                    float o = v[r] + (float)resid[(size_t)(row + r) * N + col];
                    Ch[(size_t)(row + r) * N + col] = (f16)o;
                } else if (MODE == 3) {
                    Ch[(size_t)(row + r) * N + col] = (f16)fmaxf(v[r], 0.0f);
                } else {
                    float o = v[r] + (float)resid[(size_t)(row + r) * N + col];
                    Cf[(size_t)col * M + (row + r)] = o;
                }
            }
        }
    }
}

// ---------------------------------------------------------------------------
// Q' = Xt*G^T [4096,1024,1024], 128x64 tiles, 512 blocks.
__global__ __launch_bounds__(256, 2)
void midq(const f16* Xth, const f16* GT, f16* Qp) {
    __shared__ alignas(16) f16 smem[24576];
    const int x = blockIdx.x & 7, s = blockIdx.x >> 3;  // 0..63
    const int m = x + 8 * (s >> 4), n = s & 15;
    body_nar2<0>(smem, Xth, GT, nullptr, Qp, nullptr,
                 m * 128, n * 64, 4096, 1024, 1024, 1024, 1024);
}

// ---------------------------------------------------------------------------
// Fused: scores (lower triangle, blocks 0..527) ++ RHt = HT*Xt^T (528..783).
// midrh blocks backfill into the long scores launch (R5/R8-proven).
__global__ __launch_bounds__(256, 2)
void scores_midrh(const f16* Qp, const f16* Xth, f16* Af,
                  const f16* HT, f16* RHt) {
    __shared__ alignas(16) f16 smem[32768];
    int b = blockIdx.x;
    if (b < 528) {
        const int x = b & 7;
        int s = b >> 3;  // 0..65
        int m = 0, n = 0;
#pragma unroll
        for (int q = 3; q >= 0; q--) {
            const int mm = 8 * q + ((q & 1) ? 7 - x : x);
            if (s < mm + 1) { m = mm; n = s; break; }
            s -= mm + 1;
        }
        body128sq(smem, Qp, Xth, Af, m * 128, n * 128, 4096, 1024, 1024);
    } else {
        const int r = b - 528;  // 0..255
        const int x = r & 7;
        const int s = r >> 3;   // 0..31
        const int n = x + 8 * (s >> 3), m = s & 7;
        body128sq(smem, HT, Xth, RHt, m * 128, n * 128, 4096, 1024, 1024);
    }
}

// Narrow GEMMs [M=4096, N=1024], 128x64 tiles, 512 blocks.
// CAUSAL: q-permutation {3,2,0,1} + zigzag balances K-work across CUs.
template <int MODE, bool CAUSAL_K>
__global__ __launch_bounds__(256, 2)
void gemm_nar(const f16* __restrict__ A, const f16* __restrict__ B,
              float* __restrict__ Cf, f16* __restrict__ Ch,
              const f16* __restrict__ resid, int M, int N, int K, int lda) {
    __shared__ alignas(16) f16 smem[24576];
    const int x = blockIdx.x & 7, s = blockIdx.x >> 3;  // s in 0..63
    const int qs = s >> 4, n = s & 15;
    int m;
    if (CAUSAL_K) {
        const int q = (qs == 0) ? 3 : (qs == 1) ? 2 : (qs == 2) ? 0 : 1;
        m = 8 * q + ((q & 1) ? 7 - x : x);
    } else {
        m = x + 8 * qs;
    }
    const int m0 = m * 128, n0 = n * 64;
    int Keff = K;
    if (CAUSAL_K) {
        Keff = m0 + 128;
        if (Keff > K) Keff = K;
    }
    body_nar2<MODE>(smem, A, B, Cf, Ch, resid,
                    m0, n0, M, N, K, lda, Keff);
}

// ---------------------------------------------------------------------------
extern "C" void kernel_launch(void* const* d_in, const int* in_sizes, int n_in,
                              void* d_out, int out_size, void* d_ws, size_t ws_size,
                              hipStream_t stream) {
    const int D = 1024, NT = 4096;
    const float* X = (const float*)d_in[0];
    const float* W[6] = {(const float*)d_in[1], (const float*)d_in[2],
                         (const float*)d_in[3], (const float*)d_in[4],
                         (const float*)d_in[5], (const float*)d_in[6]};
    char* ws = (char*)d_ws;
    auto MB = [](size_t x) { return x << 20; };

    // Workspace (80 MB peak):
    f16*   Xth  = (f16*)(ws + MB(0));      // [NT][D] (also f16 residual)
    f16*   Wqh  = (f16*)(ws + MB(8));
    f16*   Wkh  = (f16*)(ws + MB(10));
    f16*   Wvh  = (f16*)(ws + MB(12));
    f16*   Wot  = (f16*)(ws + MB(14));
    f16*   W4t  = (f16*)(ws + MB(16));
    f16*   W5t  = (f16*)(ws + MB(18));
    f16*   GT   = (f16*)(ws + MB(20));     // [D][D]
    f16*   HT   = (f16*)(ws + MB(22));     // [D][D]
    f16*   Qp   = (f16*)(ws + MB(24));     // [NT][D] (dead after scores)
    f16*   Af   = (f16*)(ws + MB(32));     // [NT][NT] f16 scores -> softmax A
    f16*   RHt  = (f16*)(ws + MB(64));     // [D][NT]
    f16*   Y1h  = (f16*)(ws + MB(72));     // [NT][D]
    f16*   hb   = (f16*)(ws + MB(24));     // over Qp (dead)
    float* outF = (float*)d_out;           // [D][NT]

    // 1. Weight prep (convert + transpose, R8 packing).
    prep_w<<<6144, 256, 0, stream>>>(W[0], W[1], W[2], W[3], W[4], W[5],
                                     Wqh, Wkh, Wvh, Wot, W4t, W5t, D);

    // 2. X-transpose ++ GT = Wk*Wq^T ++ HT = Wo^T*Wv^T (fused, independent).
    prepx_tiny<<<4608, 256, 0, stream>>>(X, Xth, Wkh, Wqh, GT, Wot, Wvh, HT,
                                         D, NT);

    // 3. Q' = Xt*G^T (counted dbuf).
    midq<<<512, 256, 0, stream>>>(Xth, GT, Qp);

    // 4. Scores ++ RHt = HT*Xt^T (fused, R8-proven).
    scores_midrh<<<784, 256, 0, stream>>>(Qp, Xth, Af, HT, RHt);

    // 5. Softmax in-place (2-barrier wave-reduce version).
    softmax_rows<<<NT, 256, 0, stream>>>(Af, NT);

    // 6. Y1 = Xt + A@RH (causal-K truncation, CU-pair-balanced).
    gemm_nar<2, true><<<512, 256, 0, stream>>>(
        Af, RHt, nullptr, Y1h, Xth, NT, D, NT, NT);

    // 7. h = relu(Y1 @ mlp_in).
    gemm_nar<3, false><<<512, 256, 0, stream>>>(
        Y1h, W4t, nullptr, hb, nullptr, NT, D, D, D);

    // 8. out = (Y1 + h @ mlp_out)^T.
    gemm_nar<4, false><<<512, 256, 0, stream>>>(
        hb, W5t, outF, nullptr, Y1h, NT, D, D, D);
}